// Round 18
// baseline (1603.329 us; speedup 1.0000x reference)
//
#include <hip/hip_runtime.h>

#define NPTS 131072
#define DIM 256
#define NK 128
#define NITER 10
#define SEG 16       // fallback path only
#define SLICES 128
#define PTS_PER_SLICE (NPTS / SLICES)  // 1024
#define CHUNK 128

typedef _Float16 half8 __attribute__((ext_vector_type(8)));
typedef _Float16 half4v __attribute__((ext_vector_type(4)));
typedef float f32x4 __attribute__((ext_vector_type(4)));

#define RSCALE 4096.0f
#define RINV 2.44140625e-4f  // 2^-12 exact

// ---------------------------------------------------------------------------
// x2[i] setup
// ---------------------------------------------------------------------------
__global__ void x2_kernel(const float* __restrict__ x, float* __restrict__ x2) {
  int tid = threadIdx.x;
  int p = blockIdx.x * 16 + (tid >> 4);
  int part = tid & 15;
  const float4* xr = (const float4*)(x + (size_t)p * DIM);
  float s = 0.f;
#pragma unroll
  for (int j = 0; j < 4; ++j) {
    float4 v = xr[part * 4 + j];
    s += v.x * v.x;
    s += v.y * v.y;
    s += v.z * v.z;
    s += v.w * v.w;
  }
#pragma unroll
  for (int m = 8; m >= 1; m >>= 1) s += __shfl_xor(s, m, 16);
  if (part == 0) x2[p] = s;
}

__global__ void c2_kernel(const float* __restrict__ c, float* __restrict__ c2) {
  int k = blockIdx.x, lane = threadIdx.x;
  float4 v = ((const float4*)(c + (size_t)k * DIM))[lane];
  float s = v.x * v.x + v.y * v.y + v.z * v.z + v.w * v.w;
#pragma unroll
  for (int m = 32; m >= 1; m >>= 1) s += __shfl_xor(s, m, 64);
  if (lane == 0) c2[k] = s;
}

// ---------------------------------------------------------------------------
// Fused: fp32 x -> (f16 hi, f16 scaled residual) AND x2 row-sums.
// ---------------------------------------------------------------------------
__global__ void convert_x2_kernel(const float* __restrict__ x, _Float16* __restrict__ x1,
                                  _Float16* __restrict__ x2s, float* __restrict__ x2) {
  int tid = threadIdx.x;
  int p = blockIdx.x * 16 + (tid >> 4);
  int part = tid & 15;
  const float4* xr = (const float4*)(x + (size_t)p * DIM);
  half8* o1 = (half8*)(x1 + (size_t)p * DIM);
  half8* o2 = (half8*)(x2s + (size_t)p * DIM);
  float s = 0.f;
  half8 hh[2], ll[2];
#pragma unroll
  for (int j = 0; j < 4; ++j) {
    float4 v = xr[part * 4 + j];
    float f[4] = {v.x, v.y, v.z, v.w};
#pragma unroll
    for (int u = 0; u < 4; ++u) {
      _Float16 hi = (_Float16)f[u];
      float r = f[u] - (float)hi;
      hh[j >> 1][(j & 1) * 4 + u] = hi;
      ll[j >> 1][(j & 1) * 4 + u] = (_Float16)(r * RSCALE);
      s += f[u] * f[u];
    }
  }
#pragma unroll
  for (int jj = 0; jj < 2; ++jj) {
    o1[part * 2 + jj] = hh[jj];
    o2[part * 2 + jj] = ll[jj];
  }
#pragma unroll
  for (int m = 8; m >= 1; m >>= 1) s += __shfl_xor(s, m, 16);
  if (part == 0) x2[p] = s;
}

// ---------------------------------------------------------------------------
// centroids fp32 -> chunk-tiled f16 split layout (init only)
// ---------------------------------------------------------------------------
__global__ void convert_c_kernel(const float* __restrict__ c, _Float16* __restrict__ ct) {
  int i = blockIdx.x * 256 + threadIdx.x;  // float4 index, 8192 total
  int k = i >> 6;
  int d4 = i & 63;
  float4 v = ((const float4*)c)[i];
  float f[4] = {v.x, v.y, v.z, v.w};
  half4v h, l;
#pragma unroll
  for (int j = 0; j < 4; ++j) {
    _Float16 hi = (_Float16)f[j];
    float r = f[j] - (float)hi;
    h[j] = hi;
    l[j] = (_Float16)(r * RSCALE);
  }
  int ch = d4 >> 3;
  int idx4 = ch * 2048 + k * 8 + (d4 & 7);
  ((half4v*)ct)[idx4] = h;
  ((half4v*)ct)[idx4 + 1024] = l;
}

// ---------------------------------------------------------------------------
// MFMA assignment: R16 champion body; SINGLE CHANGE vs R16: launch bounds
// (256,2) -> (256,3). VGPR cap ~170; audit says ~160 needed (acc 128 +
// A-frags 16 + addr ~15). If it fits: 3 blocks/CU = 12 waves/CU (+50%
// latency hiding on the 92MB stream). Watch WRITE_SIZE for spill.
// ---------------------------------------------------------------------------
template <bool DOHIST>
__global__ __launch_bounds__(256, 3) void assign_mfma_kernel(
    const _Float16* __restrict__ x1, const _Float16* __restrict__ x2s,
    const _Float16* __restrict__ ct, const float* __restrict__ x2,
    const float* __restrict__ c2, int* __restrict__ out, int* __restrict__ counts) {
  __shared__ __align__(16) _Float16 cbuf[2][8192];
  __shared__ int hcnt[NK];

  int tid = threadIdx.x;
  int lane = tid & 63;
  int w = tid >> 6;
  int lcol = lane & 15;
  int lgrp = lane >> 4;
  int row0 = blockIdx.x * 128 + w * 32;

  if (DOHIST && tid < NK) hcnt[tid] = 0;

  const _Float16* xa = x1 + (size_t)(row0 + lcol) * DIM + lgrp * 8;
  const _Float16* xb = x2s + (size_t)(row0 + lcol) * DIM + lgrp * 8;
  const half8* ctv = (const half8*)ct;

  f32x4 acc1[2][8], acc2[2][8];
#pragma unroll
  for (int rt = 0; rt < 2; ++rt)
#pragma unroll
    for (int c8 = 0; c8 < 8; ++c8) {
      acc1[rt][c8] = f32x4{0.f, 0.f, 0.f, 0.f};
      acc2[rt][c8] = f32x4{0.f, 0.f, 0.f, 0.f};
    }

  half8 A1[2], A2[2], nA1[2], nA2[2];

#pragma unroll
  for (int r = 0; r < 4; ++r) {
    __builtin_amdgcn_global_load_lds(
        (const __attribute__((address_space(1))) void*)(ctv + r * 256 + tid),
        (__attribute__((address_space(3))) void*)&((half8*)cbuf[0])[r * 256 + tid], 16, 0, 0);
  }
#pragma unroll
  for (int rt = 0; rt < 2; ++rt) {
    A1[rt] = *(const half8*)(xa + rt * 16 * DIM);
    A2[rt] = *(const half8*)(xb + rt * 16 * DIM);
  }
  __syncthreads();

#pragma unroll
  for (int ck = 0; ck < 8; ++ck) {
    const int cb = ck & 1;
    if (ck < 7) {
#pragma unroll
      for (int r = 0; r < 4; ++r) {
        __builtin_amdgcn_global_load_lds(
            (const __attribute__((address_space(1))) void*)(ctv + (ck + 1) * 1024 + r * 256 + tid),
            (__attribute__((address_space(3))) void*)&((half8*)cbuf[cb ^ 1])[r * 256 + tid], 16, 0,
            0);
      }
#pragma unroll
      for (int rt = 0; rt < 2; ++rt) {
        nA1[rt] = *(const half8*)(xa + rt * 16 * DIM + (ck + 1) * 32);
        nA2[rt] = *(const half8*)(xb + rt * 16 * DIM + (ck + 1) * 32);
      }
    }
#pragma unroll
    for (int c8 = 0; c8 < 8; ++c8) {
      int bidx = (c8 * 16 + lcol) * 32 + lgrp * 8;
      half8 b1 = *(const half8*)&cbuf[cb][bidx];
      half8 b2 = *(const half8*)&cbuf[cb][4096 + bidx];
#pragma unroll
      for (int rt = 0; rt < 2; ++rt) {
        acc1[rt][c8] = __builtin_amdgcn_mfma_f32_16x16x32_f16(A1[rt], b1, acc1[rt][c8], 0, 0, 0);
        acc2[rt][c8] = __builtin_amdgcn_mfma_f32_16x16x32_f16(A1[rt], b2, acc2[rt][c8], 0, 0, 0);
        acc2[rt][c8] = __builtin_amdgcn_mfma_f32_16x16x32_f16(A2[rt], b1, acc2[rt][c8], 0, 0, 0);
      }
    }
    if (ck < 7) {
#pragma unroll
      for (int rt = 0; rt < 2; ++rt) {
        A1[rt] = nA1[rt];
        A2[rt] = nA2[rt];
      }
      __syncthreads();
    }
  }

#pragma unroll
  for (int rt = 0; rt < 2; ++rt) {
    int pbase = row0 + rt * 16 + lgrp * 4;
    float x2p[4];
#pragma unroll
    for (int r = 0; r < 4; ++r) x2p[r] = x2[pbase + r];
    float bv[4];
    int bk[4];
#pragma unroll
    for (int r = 0; r < 4; ++r) { bv[r] = 3.4e38f; bk[r] = 0; }
#pragma unroll
    for (int c8 = 0; c8 < 8; ++c8) {
      int kc = c8 * 16 + lcol;
      float c2k = c2[kc];
#pragma unroll
      for (int r = 0; r < 4; ++r) {
        float dot = fmaf(acc2[rt][c8][r], RINV, acc1[rt][c8][r]);
        float d = fmaf(-2.f, dot, x2p[r]) + c2k;
        if (d < bv[r]) { bv[r] = d; bk[r] = kc; }
      }
    }
#pragma unroll
    for (int m = 1; m <= 8; m <<= 1) {
#pragma unroll
      for (int r = 0; r < 4; ++r) {
        float ov = __shfl_xor(bv[r], m, 64);
        int ok = __shfl_xor(bk[r], m, 64);
        if (ov < bv[r] || (ov == bv[r] && ok < bk[r])) { bv[r] = ov; bk[r] = ok; }
      }
    }
    if (lcol == 0) {
#pragma unroll
      for (int r = 0; r < 4; ++r) {
        out[pbase + r] = bk[r];
        if (DOHIST) atomicAdd(&hcnt[bk[r]], 1);
      }
    }
  }

  if (DOHIST) {
    __syncthreads();
    if (tid < NK) {
      int v = hcnt[tid];
      if (v) atomicAdd(&counts[tid], v);
    }
  }
}

// ---------------------------------------------------------------------------
// csum v3 (R16-exact): one-hot sum-GEMM, SLICES=128, grid 1024 = 4 blocks/CU.
// ---------------------------------------------------------------------------
__global__ __launch_bounds__(256, 4) void csum_kernel(
    const _Float16* __restrict__ x1, const _Float16* __restrict__ x2s,
    const int* __restrict__ assignb, float* __restrict__ p) {
  __shared__ __align__(16) _Float16 bt[2][2][32][136];  // [stage][arr][dim][pt pad]
  __shared__ int abuf[2][CHUNK];

  int tid = threadIdx.x;
  int lane = tid & 63;
  int w = tid >> 6;
  int slice = blockIdx.x;
  int d0 = blockIdx.y * 32;
  int ibase = slice * PTS_PER_SLICE;
  int kbase = w * 32;
  int lcol = lane & 15;
  int lgrp = lane >> 4;

  int sarr = tid >> 7;   // 0: x1, 1: x2s
  int srow = tid & 127;  // point row within chunk
  const _Float16* xsrc = sarr ? x2s : x1;

  f32x4 acc1[2][2], acc2[2][2];  // [ktile][dtile]
#pragma unroll
  for (int kt = 0; kt < 2; ++kt)
#pragma unroll
    for (int dt = 0; dt < 2; ++dt) {
      acc1[kt][dt] = f32x4{0.f, 0.f, 0.f, 0.f};
      acc2[kt][dt] = f32x4{0.f, 0.f, 0.f, 0.f};
    }

  // prologue: stage chunk 0
  {
    const half8* src = (const half8*)(xsrc + (size_t)(ibase + srow) * DIM + d0);
    half8 v[4];
#pragma unroll
    for (int q = 0; q < 4; ++q) v[q] = src[q];
#pragma unroll
    for (int q = 0; q < 4; ++q)
#pragma unroll
      for (int j = 0; j < 8; ++j) bt[0][sarr][q * 8 + j][srow] = v[q][j];
    if (tid < 32) ((int4*)abuf[0])[tid] = ((const int4*)(assignb + ibase))[tid];
  }
  __syncthreads();

  const int NCH = PTS_PER_SLICE / CHUNK;  // 8
  for (int ci = 0; ci < NCH; ++ci) {
    const int cb = ci & 1;
    half8 nv[4];
    int4 na;
    bool more = (ci < NCH - 1);
    if (more) {
      const half8* src =
          (const half8*)(xsrc + (size_t)(ibase + (ci + 1) * CHUNK + srow) * DIM + d0);
#pragma unroll
      for (int q = 0; q < 4; ++q) nv[q] = src[q];
      if (tid < 32) na = ((const int4*)(assignb + ibase + (ci + 1) * CHUNK))[tid];
    }

#pragma unroll
    for (int ks = 0; ks < 4; ++ks) {
      int4 av0 = ((int4*)abuf[cb])[ks * 8 + lgrp * 2];
      int4 av1 = ((int4*)abuf[cb])[ks * 8 + lgrp * 2 + 1];
      int aj[8] = {av0.x, av0.y, av0.z, av0.w, av1.x, av1.y, av1.z, av1.w};
      half8 oh[2];
#pragma unroll
      for (int kt = 0; kt < 2; ++kt) {
        int kk = kbase + kt * 16 + lcol;
#pragma unroll
        for (int j = 0; j < 8; ++j) oh[kt][j] = (aj[j] == kk) ? (_Float16)1.0f : (_Float16)0.0f;
      }
#pragma unroll
      for (int dt = 0; dt < 2; ++dt) {
        half8 b1 = *(const half8*)&bt[cb][0][dt * 16 + lcol][ks * 32 + lgrp * 8];
        half8 b2 = *(const half8*)&bt[cb][1][dt * 16 + lcol][ks * 32 + lgrp * 8];
#pragma unroll
        for (int kt = 0; kt < 2; ++kt) {
          acc1[kt][dt] = __builtin_amdgcn_mfma_f32_16x16x32_f16(oh[kt], b1, acc1[kt][dt], 0, 0, 0);
          acc2[kt][dt] = __builtin_amdgcn_mfma_f32_16x16x32_f16(oh[kt], b2, acc2[kt][dt], 0, 0, 0);
        }
      }
    }

    if (more) {
      __syncthreads();
#pragma unroll
      for (int q = 0; q < 4; ++q)
#pragma unroll
        for (int j = 0; j < 8; ++j) bt[cb ^ 1][sarr][q * 8 + j][srow] = nv[q][j];
      if (tid < 32) ((int4*)abuf[cb ^ 1])[tid] = na;
      __syncthreads();
    }
  }

#pragma unroll
  for (int kt = 0; kt < 2; ++kt)
#pragma unroll
    for (int dt = 0; dt < 2; ++dt) {
      int dd = d0 + dt * 16 + lcol;
#pragma unroll
      for (int r = 0; r < 4; ++r) {
        int krow = kbase + kt * 16 + lgrp * 4 + r;
        p[((size_t)slice * NK + krow) * DIM + dd] = fmaf(acc2[kt][dt][r], RINV, acc1[kt][dt][r]);
      }
    }
}

// ---------------------------------------------------------------------------
// reduce v4 (R16-exact): fixed slice order; centroids + ct + c2; counts rezero.
// ---------------------------------------------------------------------------
__global__ void reduce_v4_kernel(const float* __restrict__ p, int* __restrict__ counts,
                                 float* __restrict__ c, float* __restrict__ c2,
                                 _Float16* __restrict__ ct) {
  __shared__ float wsum[4];
  int k = blockIdx.x, d = threadIdx.x;
  int cnt = counts[k];
  float s = 0.f;
#pragma unroll 8
  for (int sl = 0; sl < SLICES; ++sl) s += p[((size_t)sl * NK + k) * DIM + d];

  float nc;
  if (cnt > 0)
    nc = s / fmaxf((float)cnt, 1.0f);
  else
    nc = c[(size_t)k * DIM + d];
  c[(size_t)k * DIM + d] = nc;

  {
    _Float16 hi = (_Float16)nc;
    float r = nc - (float)hi;
    _Float16 lov = (_Float16)(r * RSCALE);
    int ch = d >> 5, dd = d & 31;
    ct[ch * 8192 + k * 32 + dd] = hi;
    ct[ch * 8192 + k * 32 + dd + 4096] = lov;
  }

  float sq = nc * nc;
#pragma unroll
  for (int m = 32; m >= 1; m >>= 1) sq += __shfl_xor(sq, m, 64);
  if ((threadIdx.x & 63) == 0) wsum[threadIdx.x >> 6] = sq;
  __syncthreads();
  if (threadIdx.x == 0) {
    c2[k] = wsum[0] + wsum[1] + wsum[2] + wsum[3];
    counts[k] = 0;  // all threads already read cnt (pre-sync)
  }
}

// ---------------------------------------------------------------------------
// fallback path kernels (R2/R7-proven, used only if ws too small)
// ---------------------------------------------------------------------------
__global__ void assign_kernel(const float* __restrict__ x, const float* __restrict__ c,
                              const float* __restrict__ x2, const float* __restrict__ c2,
                              int* __restrict__ assign_out) {
  __shared__ float4 xs4[64 * 4];
  __shared__ float4 cs4[128 * 4];
  __shared__ float redv[64][17];
  __shared__ int redk[64][17];

  int tid = threadIdx.x;
  int tx = tid & 15;
  int ty = tid >> 4;
  int row0 = blockIdx.x * 64;

  float acc[4][8];
#pragma unroll
  for (int a = 0; a < 4; ++a)
#pragma unroll
    for (int b = 0; b < 8; ++b) acc[a][b] = 0.f;

  for (int ck = 0; ck < 16; ++ck) {
    {
      int p = tid >> 2, d4 = tid & 3;
      float4 v = *(const float4*)(x + (size_t)(row0 + p) * DIM + ck * 16 + d4 * 4);
      xs4[p * 4 + (d4 ^ ((p >> 2) & 3))] = v;
    }
#pragma unroll
    for (int r = 0; r < 2; ++r) {
      int idx = tid + r * 256;
      int kk = idx >> 2, dd = idx & 3;
      float4 v = *(const float4*)(c + (size_t)kk * DIM + ck * 16 + dd * 4);
      cs4[kk * 4 + (dd ^ ((kk >> 3) & 3))] = v;
    }
    __syncthreads();
#pragma unroll
    for (int d4 = 0; d4 < 4; ++d4) {
      float4 xr[4], cr[8];
#pragma unroll
      for (int pp = 0; pp < 4; ++pp) xr[pp] = xs4[(tx * 4 + pp) * 4 + (d4 ^ (tx & 3))];
#pragma unroll
      for (int kk = 0; kk < 8; ++kk) cr[kk] = cs4[(ty * 8 + kk) * 4 + (d4 ^ (ty & 3))];
#pragma unroll
      for (int pp = 0; pp < 4; ++pp)
#pragma unroll
        for (int kk = 0; kk < 8; ++kk) {
          acc[pp][kk] = fmaf(xr[pp].x, cr[kk].x, acc[pp][kk]);
          acc[pp][kk] = fmaf(xr[pp].y, cr[kk].y, acc[pp][kk]);
          acc[pp][kk] = fmaf(xr[pp].z, cr[kk].z, acc[pp][kk]);
          acc[pp][kk] = fmaf(xr[pp].w, cr[kk].w, acc[pp][kk]);
        }
    }
    __syncthreads();
  }

  float x2p[4];
#pragma unroll
  for (int pp = 0; pp < 4; ++pp) x2p[pp] = x2[row0 + tx * 4 + pp];

  float bestv[4];
  int bestk[4];
#pragma unroll
  for (int pp = 0; pp < 4; ++pp) { bestv[pp] = 3.4e38f; bestk[pp] = 0; }
#pragma unroll
  for (int kk = 0; kk < 8; ++kk) {
    float c2k = c2[ty * 8 + kk];
#pragma unroll
    for (int pp = 0; pp < 4; ++pp) {
      float d = fmaf(-2.f, acc[pp][kk], x2p[pp]) + c2k;
      if (d < bestv[pp]) { bestv[pp] = d; bestk[pp] = ty * 8 + kk; }
    }
  }
#pragma unroll
  for (int pp = 0; pp < 4; ++pp) {
    redv[tx * 4 + pp][ty] = bestv[pp];
    redk[tx * 4 + pp][ty] = bestk[pp];
  }
  __syncthreads();
  if (tid < 64) {
    float bv = redv[tid][0];
    int bk = redk[tid][0];
#pragma unroll
    for (int t = 1; t < 16; ++t) {
      float v = redv[tid][t];
      if (v < bv) { bv = v; bk = redk[tid][t]; }
    }
    assign_out[row0 + tid] = bk;
  }
}

__global__ void hist_kernel(const int* __restrict__ assign_in, int* __restrict__ hist) {
  __shared__ int h[NK];
  int tid = threadIdx.x, b = blockIdx.x;
  if (tid < NK) h[tid] = 0;
  __syncthreads();
#pragma unroll
  for (int r = 0; r < 4; ++r) {
    int a = assign_in[b * 1024 + r * 256 + tid];
    atomicAdd(&h[a], 1);
  }
  __syncthreads();
  if (tid < NK) hist[b * NK + tid] = h[tid];
}

__global__ void scan_fb_kernel(const int* __restrict__ hist, int* __restrict__ base,
                               int* __restrict__ counts, int* __restrict__ cbase) {
  __shared__ int h[128 * NK];
  int tid = threadIdx.x;
  for (int i = tid; i < 128 * NK; i += 256) h[i] = hist[i];
  __syncthreads();
  if (tid < NK) {
    int run = 0;
    for (int b = 0; b < 128; ++b) {
      int v = h[b * NK + tid];
      h[b * NK + tid] = run;
      run += v;
    }
    counts[tid] = run;
  }
  __syncthreads();
  if (tid == 0) {
    int cb = 0;
    for (int j = 0; j < NK; ++j) {
      cbase[j] = cb;
      cb += counts[j];
    }
  }
  __syncthreads();
  if (tid < NK) {
    int cbk = cbase[tid];
    for (int b = 0; b < 128; ++b) base[b * NK + tid] = h[b * NK + tid] + cbk;
  }
}

__global__ void scatter_kernel(const int* __restrict__ assign_in, const int* __restrict__ base,
                               int* __restrict__ perm) {
  __shared__ int cnt[NK];
  int lane = threadIdx.x, b = blockIdx.x;
  cnt[lane] = base[b * NK + lane];
  cnt[lane + 64] = base[b * NK + lane + 64];
  for (int r = 0; r < 16; ++r) {
    int p = b * 1024 + r * 64 + lane;
    int a = assign_in[p];
    unsigned long long mask = ~0ull;
#pragma unroll
    for (int j = 0; j < 7; ++j) {
      unsigned long long bal = __ballot((a >> j) & 1);
      mask &= ((a >> j) & 1) ? bal : ~bal;
    }
    int rank = __popcll(mask & ((1ull << lane) - 1ull));
    int pos = cnt[a] + rank;
    perm[pos] = p;
    if (rank == 0) cnt[a] += (int)__popcll(mask);
  }
}

__global__ void seg_sum_kernel(const float* __restrict__ x, const int* __restrict__ perm,
                               const int* __restrict__ counts, const int* __restrict__ cbase,
                               float* __restrict__ partial) {
  int k = blockIdx.x, s = blockIdx.y, d = threadIdx.x;
  int cnt = counts[k], off = cbase[k];
  int j0 = (int)(((long long)cnt * s) / SEG);
  int j1 = (int)(((long long)cnt * (s + 1)) / SEG);
  float sum = 0.f;
  int j = j0;
  for (; j + 4 <= j1; j += 4) {
    int p0 = perm[off + j + 0];
    int p1 = perm[off + j + 1];
    int p2 = perm[off + j + 2];
    int p3 = perm[off + j + 3];
    sum += x[(size_t)p0 * DIM + d];
    sum += x[(size_t)p1 * DIM + d];
    sum += x[(size_t)p2 * DIM + d];
    sum += x[(size_t)p3 * DIM + d];
  }
  for (; j < j1; ++j) sum += x[(size_t)perm[off + j] * DIM + d];
  partial[((size_t)k * SEG + s) * DIM + d] = sum;
}

__global__ void reduce_fb_kernel(const float* __restrict__ partial, const int* __restrict__ counts,
                                 float* __restrict__ c, float* __restrict__ c2) {
  __shared__ float wsum[4];
  int k = blockIdx.x, d = threadIdx.x;
  int cnt = counts[k];
  float s = 0.f;
#pragma unroll
  for (int t = 0; t < SEG; ++t) s += partial[((size_t)k * SEG + t) * DIM + d];
  float nc;
  if (cnt > 0)
    nc = s / fmaxf((float)cnt, 1.0f);
  else
    nc = c[(size_t)k * DIM + d];
  c[(size_t)k * DIM + d] = nc;
  float s2 = nc * nc;
#pragma unroll
  for (int m = 32; m >= 1; m >>= 1) s2 += __shfl_xor(s2, m, 64);
  if ((threadIdx.x & 63) == 0) wsum[threadIdx.x >> 6] = s2;
  __syncthreads();
  if (threadIdx.x == 0) c2[k] = wsum[0] + wsum[1] + wsum[2] + wsum[3];
}

// ---------------------------------------------------------------------------
extern "C" void kernel_launch(void* const* d_in, const int* in_sizes, int n_in,
                              void* d_out, int out_size, void* d_ws, size_t ws_size,
                              hipStream_t stream) {
  const float* x = (const float*)d_in[0];
  char* ws = (char*)d_ws;

  const size_t NEED_BIG = 152306688;  // ~152.3 MB
  bool use_mfma = ws_size >= NEED_BIG;

  if (use_mfma) {
    _Float16* x1 = (_Float16*)(ws + 0);          // 64 MB
    _Float16* x2s = (_Float16*)(ws + 67108864);  // 64 MB
    float* c = (float*)(ws + 134217728);         // 128 KB
    _Float16* ct = (_Float16*)(ws + 134348800);  // 128 KB
    float* c2 = (float*)(ws + 134479872);        // 512 B
    float* x2 = (float*)(ws + 134480384);        // 512 KB
    int* assignb = (int*)(ws + 135004672);       // 512 KB
    int* counts = (int*)(ws + 135528960);        // 512 B
    float* p = (float*)(ws + 135529472);         // 16 MB = 128*128*256*4

    hipMemcpyAsync(c, x, (size_t)NK * DIM * sizeof(float), hipMemcpyDeviceToDevice, stream);
    hipMemsetAsync(counts, 0, NK * sizeof(int), stream);
    convert_x2_kernel<<<NPTS / 16, 256, 0, stream>>>(x, x1, x2s, x2);
    c2_kernel<<<NK, 64, 0, stream>>>(c, c2);
    convert_c_kernel<<<NK * DIM / 4 / 256, 256, 0, stream>>>(c, ct);

    for (int it = 0; it < NITER; ++it) {
      assign_mfma_kernel<true>
          <<<NPTS / 128, 256, 0, stream>>>(x1, x2s, ct, x2, c2, assignb, counts);
      csum_kernel<<<dim3(SLICES, DIM / 32), 256, 0, stream>>>(x1, x2s, assignb, p);
      reduce_v4_kernel<<<NK, 256, 0, stream>>>(p, counts, c, c2, ct);
    }
    assign_mfma_kernel<false>
        <<<NPTS / 128, 256, 0, stream>>>(x1, x2s, ct, x2, c2, (int*)d_out, counts);
  } else {
    float* c = (float*)(ws + 0);
    float* c2 = (float*)(ws + 131072);
    float* x2 = (float*)(ws + 132096);
    int* assignb = (int*)(ws + 656384);
    int* hist = (int*)(ws + 1180672);
    int* base = (int*)(ws + 1246208);
    int* counts = (int*)(ws + 1311744);
    int* cbase = (int*)(ws + 1312256);
    int* perm = (int*)(ws + 1312768);
    float* partial = (float*)(ws + 1837056);

    hipMemcpyAsync(c, x, (size_t)NK * DIM * sizeof(float), hipMemcpyDeviceToDevice, stream);
    x2_kernel<<<NPTS / 16, 256, 0, stream>>>(x, x2);
    c2_kernel<<<NK, 64, 0, stream>>>(c, c2);

    for (int it = 0; it < NITER; ++it) {
      assign_kernel<<<NPTS / 64, 256, 0, stream>>>(x, c, x2, c2, assignb);
      hist_kernel<<<NPTS / 1024, 256, 0, stream>>>(assignb, hist);
      scan_fb_kernel<<<1, 256, 0, stream>>>(hist, base, counts, cbase);
      scatter_kernel<<<NPTS / 1024, 64, 0, stream>>>(assignb, base, perm);
      seg_sum_kernel<<<dim3(NK, SEG), 256, 0, stream>>>(x, perm, counts, cbase, partial);
      reduce_fb_kernel<<<NK, 256, 0, stream>>>(partial, counts, c, c2);
    }
    assign_kernel<<<NPTS / 64, 256, 0, stream>>>(x, c, x2, c2, (int*)d_out);
  }
}

// Round 19
// 981.292 us; speedup vs baseline: 1.6339x; 1.6339x over previous
//
#include <hip/hip_runtime.h>

#define NPTS 131072
#define DIM 256
#define NK 128
#define NITER 10
#define SEG 16       // fallback path only
#define SLICES 128
#define PTS_PER_SLICE (NPTS / SLICES)  // 1024
#define CHUNK 128

typedef _Float16 half8 __attribute__((ext_vector_type(8)));
typedef _Float16 half4v __attribute__((ext_vector_type(4)));
typedef float f32x4 __attribute__((ext_vector_type(4)));

#define RSCALE 4096.0f
#define RINV 2.44140625e-4f  // 2^-12 exact

// ---------------------------------------------------------------------------
// x2[i] setup
// ---------------------------------------------------------------------------
__global__ void x2_kernel(const float* __restrict__ x, float* __restrict__ x2) {
  int tid = threadIdx.x;
  int p = blockIdx.x * 16 + (tid >> 4);
  int part = tid & 15;
  const float4* xr = (const float4*)(x + (size_t)p * DIM);
  float s = 0.f;
#pragma unroll
  for (int j = 0; j < 4; ++j) {
    float4 v = xr[part * 4 + j];
    s += v.x * v.x;
    s += v.y * v.y;
    s += v.z * v.z;
    s += v.w * v.w;
  }
#pragma unroll
  for (int m = 8; m >= 1; m >>= 1) s += __shfl_xor(s, m, 16);
  if (part == 0) x2[p] = s;
}

__global__ void c2_kernel(const float* __restrict__ c, float* __restrict__ c2) {
  int k = blockIdx.x, lane = threadIdx.x;
  float4 v = ((const float4*)(c + (size_t)k * DIM))[lane];
  float s = v.x * v.x + v.y * v.y + v.z * v.z + v.w * v.w;
#pragma unroll
  for (int m = 32; m >= 1; m >>= 1) s += __shfl_xor(s, m, 64);
  if (lane == 0) c2[k] = s;
}

// ---------------------------------------------------------------------------
// Fused: fp32 x -> (f16 hi, f16 scaled residual) AND x2 row-sums.
// ---------------------------------------------------------------------------
__global__ void convert_x2_kernel(const float* __restrict__ x, _Float16* __restrict__ x1,
                                  _Float16* __restrict__ x2s, float* __restrict__ x2) {
  int tid = threadIdx.x;
  int p = blockIdx.x * 16 + (tid >> 4);
  int part = tid & 15;
  const float4* xr = (const float4*)(x + (size_t)p * DIM);
  half8* o1 = (half8*)(x1 + (size_t)p * DIM);
  half8* o2 = (half8*)(x2s + (size_t)p * DIM);
  float s = 0.f;
  half8 hh[2], ll[2];
#pragma unroll
  for (int j = 0; j < 4; ++j) {
    float4 v = xr[part * 4 + j];
    float f[4] = {v.x, v.y, v.z, v.w};
#pragma unroll
    for (int u = 0; u < 4; ++u) {
      _Float16 hi = (_Float16)f[u];
      float r = f[u] - (float)hi;
      hh[j >> 1][(j & 1) * 4 + u] = hi;
      ll[j >> 1][(j & 1) * 4 + u] = (_Float16)(r * RSCALE);
      s += f[u] * f[u];
    }
  }
#pragma unroll
  for (int jj = 0; jj < 2; ++jj) {
    o1[part * 2 + jj] = hh[jj];
    o2[part * 2 + jj] = ll[jj];
  }
#pragma unroll
  for (int m = 8; m >= 1; m >>= 1) s += __shfl_xor(s, m, 16);
  if (part == 0) x2[p] = s;
}

// ---------------------------------------------------------------------------
// centroids fp32 -> chunk-tiled f16 split layout (init only)
// ---------------------------------------------------------------------------
__global__ void convert_c_kernel(const float* __restrict__ c, _Float16* __restrict__ ct) {
  int i = blockIdx.x * 256 + threadIdx.x;  // float4 index, 8192 total
  int k = i >> 6;
  int d4 = i & 63;
  float4 v = ((const float4*)c)[i];
  float f[4] = {v.x, v.y, v.z, v.w};
  half4v h, l;
#pragma unroll
  for (int j = 0; j < 4; ++j) {
    _Float16 hi = (_Float16)f[j];
    float r = f[j] - (float)hi;
    h[j] = hi;
    l[j] = (_Float16)(r * RSCALE);
  }
  int ch = d4 >> 3;
  int idx4 = ch * 2048 + k * 8 + (d4 & 7);
  ((half4v*)ct)[idx4] = h;
  ((half4v*)ct)[idx4 + 1024] = l;
}

// ---------------------------------------------------------------------------
// MFMA assignment (R16 champion, exact): 32 pts/wave, (256,2), dual acc,
// A-prefetch, ct staging via global_load_lds width=16.
// Occupancy sweep verdict: (256,2) no-spill champion; (256,3)/(256,4) spill.
// ---------------------------------------------------------------------------
template <bool DOHIST>
__global__ __launch_bounds__(256, 2) void assign_mfma_kernel(
    const _Float16* __restrict__ x1, const _Float16* __restrict__ x2s,
    const _Float16* __restrict__ ct, const float* __restrict__ x2,
    const float* __restrict__ c2, int* __restrict__ out, int* __restrict__ counts) {
  __shared__ __align__(16) _Float16 cbuf[2][8192];
  __shared__ int hcnt[NK];

  int tid = threadIdx.x;
  int lane = tid & 63;
  int w = tid >> 6;
  int lcol = lane & 15;
  int lgrp = lane >> 4;
  int row0 = blockIdx.x * 128 + w * 32;

  if (DOHIST && tid < NK) hcnt[tid] = 0;

  const _Float16* xa = x1 + (size_t)(row0 + lcol) * DIM + lgrp * 8;
  const _Float16* xb = x2s + (size_t)(row0 + lcol) * DIM + lgrp * 8;
  const half8* ctv = (const half8*)ct;

  f32x4 acc1[2][8], acc2[2][8];
#pragma unroll
  for (int rt = 0; rt < 2; ++rt)
#pragma unroll
    for (int c8 = 0; c8 < 8; ++c8) {
      acc1[rt][c8] = f32x4{0.f, 0.f, 0.f, 0.f};
      acc2[rt][c8] = f32x4{0.f, 0.f, 0.f, 0.f};
    }

  half8 A1[2], A2[2], nA1[2], nA2[2];

#pragma unroll
  for (int r = 0; r < 4; ++r) {
    __builtin_amdgcn_global_load_lds(
        (const __attribute__((address_space(1))) void*)(ctv + r * 256 + tid),
        (__attribute__((address_space(3))) void*)&((half8*)cbuf[0])[r * 256 + tid], 16, 0, 0);
  }
#pragma unroll
  for (int rt = 0; rt < 2; ++rt) {
    A1[rt] = *(const half8*)(xa + rt * 16 * DIM);
    A2[rt] = *(const half8*)(xb + rt * 16 * DIM);
  }
  __syncthreads();

#pragma unroll
  for (int ck = 0; ck < 8; ++ck) {
    const int cb = ck & 1;
    if (ck < 7) {
#pragma unroll
      for (int r = 0; r < 4; ++r) {
        __builtin_amdgcn_global_load_lds(
            (const __attribute__((address_space(1))) void*)(ctv + (ck + 1) * 1024 + r * 256 + tid),
            (__attribute__((address_space(3))) void*)&((half8*)cbuf[cb ^ 1])[r * 256 + tid], 16, 0,
            0);
      }
#pragma unroll
      for (int rt = 0; rt < 2; ++rt) {
        nA1[rt] = *(const half8*)(xa + rt * 16 * DIM + (ck + 1) * 32);
        nA2[rt] = *(const half8*)(xb + rt * 16 * DIM + (ck + 1) * 32);
      }
    }
#pragma unroll
    for (int c8 = 0; c8 < 8; ++c8) {
      int bidx = (c8 * 16 + lcol) * 32 + lgrp * 8;
      half8 b1 = *(const half8*)&cbuf[cb][bidx];
      half8 b2 = *(const half8*)&cbuf[cb][4096 + bidx];
#pragma unroll
      for (int rt = 0; rt < 2; ++rt) {
        acc1[rt][c8] = __builtin_amdgcn_mfma_f32_16x16x32_f16(A1[rt], b1, acc1[rt][c8], 0, 0, 0);
        acc2[rt][c8] = __builtin_amdgcn_mfma_f32_16x16x32_f16(A1[rt], b2, acc2[rt][c8], 0, 0, 0);
        acc2[rt][c8] = __builtin_amdgcn_mfma_f32_16x16x32_f16(A2[rt], b1, acc2[rt][c8], 0, 0, 0);
      }
    }
    if (ck < 7) {
#pragma unroll
      for (int rt = 0; rt < 2; ++rt) {
        A1[rt] = nA1[rt];
        A2[rt] = nA2[rt];
      }
      __syncthreads();
    }
  }

#pragma unroll
  for (int rt = 0; rt < 2; ++rt) {
    int pbase = row0 + rt * 16 + lgrp * 4;
    float x2p[4];
#pragma unroll
    for (int r = 0; r < 4; ++r) x2p[r] = x2[pbase + r];
    float bv[4];
    int bk[4];
#pragma unroll
    for (int r = 0; r < 4; ++r) { bv[r] = 3.4e38f; bk[r] = 0; }
#pragma unroll
    for (int c8 = 0; c8 < 8; ++c8) {
      int kc = c8 * 16 + lcol;
      float c2k = c2[kc];
#pragma unroll
      for (int r = 0; r < 4; ++r) {
        float dot = fmaf(acc2[rt][c8][r], RINV, acc1[rt][c8][r]);
        float d = fmaf(-2.f, dot, x2p[r]) + c2k;
        if (d < bv[r]) { bv[r] = d; bk[r] = kc; }
      }
    }
#pragma unroll
    for (int m = 1; m <= 8; m <<= 1) {
#pragma unroll
      for (int r = 0; r < 4; ++r) {
        float ov = __shfl_xor(bv[r], m, 64);
        int ok = __shfl_xor(bk[r], m, 64);
        if (ov < bv[r] || (ov == bv[r] && ok < bk[r])) { bv[r] = ov; bk[r] = ok; }
      }
    }
    if (lcol == 0) {
#pragma unroll
      for (int r = 0; r < 4; ++r) {
        out[pbase + r] = bk[r];
        if (DOHIST) atomicAdd(&hcnt[bk[r]], 1);
      }
    }
  }

  if (DOHIST) {
    __syncthreads();
    if (tid < NK) {
      int v = hcnt[tid];
      if (v) atomicAdd(&counts[tid], v);
    }
  }
}

// ---------------------------------------------------------------------------
// csum v3 (R16-exact): one-hot sum-GEMM, SLICES=128, grid 1024 = 4 blocks/CU.
// ---------------------------------------------------------------------------
__global__ __launch_bounds__(256, 4) void csum_kernel(
    const _Float16* __restrict__ x1, const _Float16* __restrict__ x2s,
    const int* __restrict__ assignb, float* __restrict__ p) {
  __shared__ __align__(16) _Float16 bt[2][2][32][136];  // [stage][arr][dim][pt pad]
  __shared__ int abuf[2][CHUNK];

  int tid = threadIdx.x;
  int lane = tid & 63;
  int w = tid >> 6;
  int slice = blockIdx.x;
  int d0 = blockIdx.y * 32;
  int ibase = slice * PTS_PER_SLICE;
  int kbase = w * 32;
  int lcol = lane & 15;
  int lgrp = lane >> 4;

  int sarr = tid >> 7;   // 0: x1, 1: x2s
  int srow = tid & 127;  // point row within chunk
  const _Float16* xsrc = sarr ? x2s : x1;

  f32x4 acc1[2][2], acc2[2][2];  // [ktile][dtile]
#pragma unroll
  for (int kt = 0; kt < 2; ++kt)
#pragma unroll
    for (int dt = 0; dt < 2; ++dt) {
      acc1[kt][dt] = f32x4{0.f, 0.f, 0.f, 0.f};
      acc2[kt][dt] = f32x4{0.f, 0.f, 0.f, 0.f};
    }

  // prologue: stage chunk 0
  {
    const half8* src = (const half8*)(xsrc + (size_t)(ibase + srow) * DIM + d0);
    half8 v[4];
#pragma unroll
    for (int q = 0; q < 4; ++q) v[q] = src[q];
#pragma unroll
    for (int q = 0; q < 4; ++q)
#pragma unroll
      for (int j = 0; j < 8; ++j) bt[0][sarr][q * 8 + j][srow] = v[q][j];
    if (tid < 32) ((int4*)abuf[0])[tid] = ((const int4*)(assignb + ibase))[tid];
  }
  __syncthreads();

  const int NCH = PTS_PER_SLICE / CHUNK;  // 8
  for (int ci = 0; ci < NCH; ++ci) {
    const int cb = ci & 1;
    half8 nv[4];
    int4 na;
    bool more = (ci < NCH - 1);
    if (more) {
      const half8* src =
          (const half8*)(xsrc + (size_t)(ibase + (ci + 1) * CHUNK + srow) * DIM + d0);
#pragma unroll
      for (int q = 0; q < 4; ++q) nv[q] = src[q];
      if (tid < 32) na = ((const int4*)(assignb + ibase + (ci + 1) * CHUNK))[tid];
    }

#pragma unroll
    for (int ks = 0; ks < 4; ++ks) {
      int4 av0 = ((int4*)abuf[cb])[ks * 8 + lgrp * 2];
      int4 av1 = ((int4*)abuf[cb])[ks * 8 + lgrp * 2 + 1];
      int aj[8] = {av0.x, av0.y, av0.z, av0.w, av1.x, av1.y, av1.z, av1.w};
      half8 oh[2];
#pragma unroll
      for (int kt = 0; kt < 2; ++kt) {
        int kk = kbase + kt * 16 + lcol;
#pragma unroll
        for (int j = 0; j < 8; ++j) oh[kt][j] = (aj[j] == kk) ? (_Float16)1.0f : (_Float16)0.0f;
      }
#pragma unroll
      for (int dt = 0; dt < 2; ++dt) {
        half8 b1 = *(const half8*)&bt[cb][0][dt * 16 + lcol][ks * 32 + lgrp * 8];
        half8 b2 = *(const half8*)&bt[cb][1][dt * 16 + lcol][ks * 32 + lgrp * 8];
#pragma unroll
        for (int kt = 0; kt < 2; ++kt) {
          acc1[kt][dt] = __builtin_amdgcn_mfma_f32_16x16x32_f16(oh[kt], b1, acc1[kt][dt], 0, 0, 0);
          acc2[kt][dt] = __builtin_amdgcn_mfma_f32_16x16x32_f16(oh[kt], b2, acc2[kt][dt], 0, 0, 0);
        }
      }
    }

    if (more) {
      __syncthreads();
#pragma unroll
      for (int q = 0; q < 4; ++q)
#pragma unroll
        for (int j = 0; j < 8; ++j) bt[cb ^ 1][sarr][q * 8 + j][srow] = nv[q][j];
      if (tid < 32) ((int4*)abuf[cb ^ 1])[tid] = na;
      __syncthreads();
    }
  }

#pragma unroll
  for (int kt = 0; kt < 2; ++kt)
#pragma unroll
    for (int dt = 0; dt < 2; ++dt) {
      int dd = d0 + dt * 16 + lcol;
#pragma unroll
      for (int r = 0; r < 4; ++r) {
        int krow = kbase + kt * 16 + lgrp * 4 + r;
        p[((size_t)slice * NK + krow) * DIM + dd] = fmaf(acc2[kt][dt][r], RINV, acc1[kt][dt][r]);
      }
    }
}

// ---------------------------------------------------------------------------
// reduce v4 (R16-exact): fixed slice order; centroids + ct + c2; counts rezero.
// ---------------------------------------------------------------------------
__global__ void reduce_v4_kernel(const float* __restrict__ p, int* __restrict__ counts,
                                 float* __restrict__ c, float* __restrict__ c2,
                                 _Float16* __restrict__ ct) {
  __shared__ float wsum[4];
  int k = blockIdx.x, d = threadIdx.x;
  int cnt = counts[k];
  float s = 0.f;
#pragma unroll 8
  for (int sl = 0; sl < SLICES; ++sl) s += p[((size_t)sl * NK + k) * DIM + d];

  float nc;
  if (cnt > 0)
    nc = s / fmaxf((float)cnt, 1.0f);
  else
    nc = c[(size_t)k * DIM + d];
  c[(size_t)k * DIM + d] = nc;

  {
    _Float16 hi = (_Float16)nc;
    float r = nc - (float)hi;
    _Float16 lov = (_Float16)(r * RSCALE);
    int ch = d >> 5, dd = d & 31;
    ct[ch * 8192 + k * 32 + dd] = hi;
    ct[ch * 8192 + k * 32 + dd + 4096] = lov;
  }

  float sq = nc * nc;
#pragma unroll
  for (int m = 32; m >= 1; m >>= 1) sq += __shfl_xor(sq, m, 64);
  if ((threadIdx.x & 63) == 0) wsum[threadIdx.x >> 6] = sq;
  __syncthreads();
  if (threadIdx.x == 0) {
    c2[k] = wsum[0] + wsum[1] + wsum[2] + wsum[3];
    counts[k] = 0;  // all threads already read cnt (pre-sync)
  }
}

// ---------------------------------------------------------------------------
// fallback path kernels (R2/R7-proven, used only if ws too small)
// ---------------------------------------------------------------------------
__global__ void assign_kernel(const float* __restrict__ x, const float* __restrict__ c,
                              const float* __restrict__ x2, const float* __restrict__ c2,
                              int* __restrict__ assign_out) {
  __shared__ float4 xs4[64 * 4];
  __shared__ float4 cs4[128 * 4];
  __shared__ float redv[64][17];
  __shared__ int redk[64][17];

  int tid = threadIdx.x;
  int tx = tid & 15;
  int ty = tid >> 4;
  int row0 = blockIdx.x * 64;

  float acc[4][8];
#pragma unroll
  for (int a = 0; a < 4; ++a)
#pragma unroll
    for (int b = 0; b < 8; ++b) acc[a][b] = 0.f;

  for (int ck = 0; ck < 16; ++ck) {
    {
      int p = tid >> 2, d4 = tid & 3;
      float4 v = *(const float4*)(x + (size_t)(row0 + p) * DIM + ck * 16 + d4 * 4);
      xs4[p * 4 + (d4 ^ ((p >> 2) & 3))] = v;
    }
#pragma unroll
    for (int r = 0; r < 2; ++r) {
      int idx = tid + r * 256;
      int kk = idx >> 2, dd = idx & 3;
      float4 v = *(const float4*)(c + (size_t)kk * DIM + ck * 16 + dd * 4);
      cs4[kk * 4 + (dd ^ ((kk >> 3) & 3))] = v;
    }
    __syncthreads();
#pragma unroll
    for (int d4 = 0; d4 < 4; ++d4) {
      float4 xr[4], cr[8];
#pragma unroll
      for (int pp = 0; pp < 4; ++pp) xr[pp] = xs4[(tx * 4 + pp) * 4 + (d4 ^ (tx & 3))];
#pragma unroll
      for (int kk = 0; kk < 8; ++kk) cr[kk] = cs4[(ty * 8 + kk) * 4 + (d4 ^ (ty & 3))];
#pragma unroll
      for (int pp = 0; pp < 4; ++pp)
#pragma unroll
        for (int kk = 0; kk < 8; ++kk) {
          acc[pp][kk] = fmaf(xr[pp].x, cr[kk].x, acc[pp][kk]);
          acc[pp][kk] = fmaf(xr[pp].y, cr[kk].y, acc[pp][kk]);
          acc[pp][kk] = fmaf(xr[pp].z, cr[kk].z, acc[pp][kk]);
          acc[pp][kk] = fmaf(xr[pp].w, cr[kk].w, acc[pp][kk]);
        }
    }
    __syncthreads();
  }

  float x2p[4];
#pragma unroll
  for (int pp = 0; pp < 4; ++pp) x2p[pp] = x2[row0 + tx * 4 + pp];

  float bestv[4];
  int bestk[4];
#pragma unroll
  for (int pp = 0; pp < 4; ++pp) { bestv[pp] = 3.4e38f; bestk[pp] = 0; }
#pragma unroll
  for (int kk = 0; kk < 8; ++kk) {
    float c2k = c2[ty * 8 + kk];
#pragma unroll
    for (int pp = 0; pp < 4; ++pp) {
      float d = fmaf(-2.f, acc[pp][kk], x2p[pp]) + c2k;
      if (d < bestv[pp]) { bestv[pp] = d; bestk[pp] = ty * 8 + kk; }
    }
  }
#pragma unroll
  for (int pp = 0; pp < 4; ++pp) {
    redv[tx * 4 + pp][ty] = bestv[pp];
    redk[tx * 4 + pp][ty] = bestk[pp];
  }
  __syncthreads();
  if (tid < 64) {
    float bv = redv[tid][0];
    int bk = redk[tid][0];
#pragma unroll
    for (int t = 1; t < 16; ++t) {
      float v = redv[tid][t];
      if (v < bv) { bv = v; bk = redk[tid][t]; }
    }
    assign_out[row0 + tid] = bk;
  }
}

__global__ void hist_kernel(const int* __restrict__ assign_in, int* __restrict__ hist) {
  __shared__ int h[NK];
  int tid = threadIdx.x, b = blockIdx.x;
  if (tid < NK) h[tid] = 0;
  __syncthreads();
#pragma unroll
  for (int r = 0; r < 4; ++r) {
    int a = assign_in[b * 1024 + r * 256 + tid];
    atomicAdd(&h[a], 1);
  }
  __syncthreads();
  if (tid < NK) hist[b * NK + tid] = h[tid];
}

__global__ void scan_fb_kernel(const int* __restrict__ hist, int* __restrict__ base,
                               int* __restrict__ counts, int* __restrict__ cbase) {
  __shared__ int h[128 * NK];
  int tid = threadIdx.x;
  for (int i = tid; i < 128 * NK; i += 256) h[i] = hist[i];
  __syncthreads();
  if (tid < NK) {
    int run = 0;
    for (int b = 0; b < 128; ++b) {
      int v = h[b * NK + tid];
      h[b * NK + tid] = run;
      run += v;
    }
    counts[tid] = run;
  }
  __syncthreads();
  if (tid == 0) {
    int cb = 0;
    for (int j = 0; j < NK; ++j) {
      cbase[j] = cb;
      cb += counts[j];
    }
  }
  __syncthreads();
  if (tid < NK) {
    int cbk = cbase[tid];
    for (int b = 0; b < 128; ++b) base[b * NK + tid] = h[b * NK + tid] + cbk;
  }
}

__global__ void scatter_kernel(const int* __restrict__ assign_in, const int* __restrict__ base,
                               int* __restrict__ perm) {
  __shared__ int cnt[NK];
  int lane = threadIdx.x, b = blockIdx.x;
  cnt[lane] = base[b * NK + lane];
  cnt[lane + 64] = base[b * NK + lane + 64];
  for (int r = 0; r < 16; ++r) {
    int p = b * 1024 + r * 64 + lane;
    int a = assign_in[p];
    unsigned long long mask = ~0ull;
#pragma unroll
    for (int j = 0; j < 7; ++j) {
      unsigned long long bal = __ballot((a >> j) & 1);
      mask &= ((a >> j) & 1) ? bal : ~bal;
    }
    int rank = __popcll(mask & ((1ull << lane) - 1ull));
    int pos = cnt[a] + rank;
    perm[pos] = p;
    if (rank == 0) cnt[a] += (int)__popcll(mask);
  }
}

__global__ void seg_sum_kernel(const float* __restrict__ x, const int* __restrict__ perm,
                               const int* __restrict__ counts, const int* __restrict__ cbase,
                               float* __restrict__ partial) {
  int k = blockIdx.x, s = blockIdx.y, d = threadIdx.x;
  int cnt = counts[k], off = cbase[k];
  int j0 = (int)(((long long)cnt * s) / SEG);
  int j1 = (int)(((long long)cnt * (s + 1)) / SEG);
  float sum = 0.f;
  int j = j0;
  for (; j + 4 <= j1; j += 4) {
    int p0 = perm[off + j + 0];
    int p1 = perm[off + j + 1];
    int p2 = perm[off + j + 2];
    int p3 = perm[off + j + 3];
    sum += x[(size_t)p0 * DIM + d];
    sum += x[(size_t)p1 * DIM + d];
    sum += x[(size_t)p2 * DIM + d];
    sum += x[(size_t)p3 * DIM + d];
  }
  for (; j < j1; ++j) sum += x[(size_t)perm[off + j] * DIM + d];
  partial[((size_t)k * SEG + s) * DIM + d] = sum;
}

__global__ void reduce_fb_kernel(const float* __restrict__ partial, const int* __restrict__ counts,
                                 float* __restrict__ c, float* __restrict__ c2) {
  __shared__ float wsum[4];
  int k = blockIdx.x, d = threadIdx.x;
  int cnt = counts[k];
  float s = 0.f;
#pragma unroll
  for (int t = 0; t < SEG; ++t) s += partial[((size_t)k * SEG + t) * DIM + d];
  float nc;
  if (cnt > 0)
    nc = s / fmaxf((float)cnt, 1.0f);
  else
    nc = c[(size_t)k * DIM + d];
  c[(size_t)k * DIM + d] = nc;
  float s2 = nc * nc;
#pragma unroll
  for (int m = 32; m >= 1; m >>= 1) s2 += __shfl_xor(s2, m, 64);
  if ((threadIdx.x & 63) == 0) wsum[threadIdx.x >> 6] = s2;
  __syncthreads();
  if (threadIdx.x == 0) c2[k] = wsum[0] + wsum[1] + wsum[2] + wsum[3];
}

// ---------------------------------------------------------------------------
extern "C" void kernel_launch(void* const* d_in, const int* in_sizes, int n_in,
                              void* d_out, int out_size, void* d_ws, size_t ws_size,
                              hipStream_t stream) {
  const float* x = (const float*)d_in[0];
  char* ws = (char*)d_ws;

  const size_t NEED_BIG = 152306688;  // ~152.3 MB
  bool use_mfma = ws_size >= NEED_BIG;

  if (use_mfma) {
    _Float16* x1 = (_Float16*)(ws + 0);          // 64 MB
    _Float16* x2s = (_Float16*)(ws + 67108864);  // 64 MB
    float* c = (float*)(ws + 134217728);         // 128 KB
    _Float16* ct = (_Float16*)(ws + 134348800);  // 128 KB
    float* c2 = (float*)(ws + 134479872);        // 512 B
    float* x2 = (float*)(ws + 134480384);        // 512 KB
    int* assignb = (int*)(ws + 135004672);       // 512 KB
    int* counts = (int*)(ws + 135528960);        // 512 B
    float* p = (float*)(ws + 135529472);         // 16 MB = 128*128*256*4

    hipMemcpyAsync(c, x, (size_t)NK * DIM * sizeof(float), hipMemcpyDeviceToDevice, stream);
    hipMemsetAsync(counts, 0, NK * sizeof(int), stream);
    convert_x2_kernel<<<NPTS / 16, 256, 0, stream>>>(x, x1, x2s, x2);
    c2_kernel<<<NK, 64, 0, stream>>>(c, c2);
    convert_c_kernel<<<NK * DIM / 4 / 256, 256, 0, stream>>>(c, ct);

    for (int it = 0; it < NITER; ++it) {
      assign_mfma_kernel<true>
          <<<NPTS / 128, 256, 0, stream>>>(x1, x2s, ct, x2, c2, assignb, counts);
      csum_kernel<<<dim3(SLICES, DIM / 32), 256, 0, stream>>>(x1, x2s, assignb, p);
      reduce_v4_kernel<<<NK, 256, 0, stream>>>(p, counts, c, c2, ct);
    }
    assign_mfma_kernel<false>
        <<<NPTS / 128, 256, 0, stream>>>(x1, x2s, ct, x2, c2, (int*)d_out, counts);
  } else {
    float* c = (float*)(ws + 0);
    float* c2 = (float*)(ws + 131072);
    float* x2 = (float*)(ws + 132096);
    int* assignb = (int*)(ws + 656384);
    int* hist = (int*)(ws + 1180672);
    int* base = (int*)(ws + 1246208);
    int* counts = (int*)(ws + 1311744);
    int* cbase = (int*)(ws + 1312256);
    int* perm = (int*)(ws + 1312768);
    float* partial = (float*)(ws + 1837056);

    hipMemcpyAsync(c, x, (size_t)NK * DIM * sizeof(float), hipMemcpyDeviceToDevice, stream);
    x2_kernel<<<NPTS / 16, 256, 0, stream>>>(x, x2);
    c2_kernel<<<NK, 64, 0, stream>>>(c, c2);

    for (int it = 0; it < NITER; ++it) {
      assign_kernel<<<NPTS / 64, 256, 0, stream>>>(x, c, x2, c2, assignb);
      hist_kernel<<<NPTS / 1024, 256, 0, stream>>>(assignb, hist);
      scan_fb_kernel<<<1, 256, 0, stream>>>(hist, base, counts, cbase);
      scatter_kernel<<<NPTS / 1024, 64, 0, stream>>>(assignb, base, perm);
      seg_sum_kernel<<<dim3(NK, SEG), 256, 0, stream>>>(x, perm, counts, cbase, partial);
      reduce_fb_kernel<<<NK, 256, 0, stream>>>(partial, counts, c, c2);
    }
    assign_kernel<<<NPTS / 64, 256, 0, stream>>>(x, c, x2, c2, (int*)d_out);
  }
}